// Round 3
// baseline (145.143 us; speedup 1.0000x reference)
//
#include <hip/hip_runtime.h>

typedef _Float16 half8 __attribute__((ext_vector_type(8)));
typedef float f32x4 __attribute__((ext_vector_type(4)));
typedef unsigned short u16x8 __attribute__((ext_vector_type(8)));

#define LOG2E 1.44269504088896340736f

constexpr int NB = 16, LQ = 1024, LK = 1024, DX = 512, DVD = 512;
constexpr int QBLK = 64, KVB = 32, NCH = LK / KVB;
constexpr int KTILE = KVB * DX;   // 16384 u16 per K buffer
constexpr int VTILE = KVB * DVD;  // 16384 u16 per V buffer

static __device__ __forceinline__ unsigned short f2h(float f) {
  union { _Float16 h; unsigned short u; } c; c.h = (_Float16)f; return c.u;
}
static __device__ __forceinline__ unsigned int pack2(float a, float b) {
  union { _Float16 h[2]; unsigned int u; } c;
  c.h[0] = (_Float16)a; c.h[1] = (_Float16)b; return c.u;
}

static __device__ __forceinline__ void gload16(const unsigned short* g, unsigned short* l) {
  __builtin_amdgcn_global_load_lds(
      (const __attribute__((address_space(1))) unsigned int*)g,
      (__attribute__((address_space(3))) unsigned int*)l, 16, 0, 0);
}

// ---- prep 1: K f32 -> f16, same [b][k][x] layout
__global__ void cvt_k(const float* __restrict__ K, unsigned short* __restrict__ Kh) {
  size_t i = ((size_t)blockIdx.x * 256 + threadIdx.x) * 8;
  float4 a = *(const float4*)(K + i);
  float4 b = *(const float4*)(K + i + 4);
  u16x8 o = { f2h(a.x), f2h(a.y), f2h(a.z), f2h(a.w),
              f2h(b.x), f2h(b.y), f2h(b.z), f2h(b.w) };
  *(u16x8*)(Kh + i) = o;
}

// ---- prep 2: V [b][k][d] f32 -> Vt [b][d][k] f16 (64x64 LDS tiles)
__global__ void cvt_transpose_v(const float* __restrict__ V, unsigned short* __restrict__ Vt) {
  __shared__ float tile[64][65];
  const int bidx = blockIdx.x;          // 16 b * 16 ktiles * 8 dtiles
  const int b  = bidx >> 7;
  const int kt = (bidx >> 3) & 15;
  const int dt = bidx & 7;
  const int t = threadIdx.x;            // 256
  const int r  = t >> 4;
  const int c4 = (t & 15) * 4;
  const float* src = V + ((size_t)b * LK + kt * 64) * DVD + dt * 64;
#pragma unroll
  for (int i = 0; i < 4; ++i) {
    float4 v = *(const float4*)(src + (size_t)(r + i * 16) * DVD + c4);
    tile[r + i * 16][c4 + 0] = v.x; tile[r + i * 16][c4 + 1] = v.y;
    tile[r + i * 16][c4 + 2] = v.z; tile[r + i * 16][c4 + 3] = v.w;
  }
  __syncthreads();
  const int dr  = t >> 2;
  const int seg = t & 3;
  unsigned short ob[16];
#pragma unroll
  for (int i = 0; i < 16; ++i) ob[i] = f2h(tile[seg * 16 + i][dr]);
  unsigned short* dst = Vt + ((size_t)b * DVD + dt * 64 + dr) * LK + kt * 64 + seg * 16;
  *(u16x8*)dst = *(const u16x8*)&ob[0];
  *(u16x8*)(dst + 8) = *(const u16x8*)&ob[8];
}

// ---- main fused attention: per-wave-independent softmax (swapped QK^T)
__global__ __launch_bounds__(512, 2) void attn_fused3(
    const float* __restrict__ Qf, const unsigned short* __restrict__ Kh,
    const unsigned short* __restrict__ Vt, float* __restrict__ Out) {
  // K layout: [buf][part=x/8 (64)][kv (32)][8]   part stride 256 u16
  // V layout: [buf][pv=kvloc/8 (4)][d (512)][8]  pv stride 4096 u16
  // P layout: per-wave [pp=kv/8 (4)][q (16)][8]  pp stride 128 u16
  __shared__ __align__(16) unsigned short Kl[2][KTILE];
  __shared__ __align__(16) unsigned short Vl[2][VTILE];
  __shared__ __align__(16) unsigned short Pl[8][512];
  __shared__ __align__(16) float sml[8][16];

  const int bid = blockIdx.x;
  const int logical = (bid & 7) * 32 + (bid >> 3);  // XCD-chunked: 2 batches/XCD
  const int b  = logical >> 4;
  const int qt = logical & 15;
  const int tid = (int)threadIdx.x;
  const int lane = tid & 63;
  const int wave = tid >> 6;            // 0..7
  const int wq = wave >> 1, wd = wave & 1;
  const int q0 = qt * QBLK + wq * 16;
  const int d0 = wd * 256;
  const int c15 = lane & 15;
  const int g4  = lane >> 4;
  const int rbase = g4 * 4;

  // ---- Q fragments (pre-scaled by LOG2E so softmax uses raw exp2)
  half8 qfrag[16];
  {
    const float* qrow = Qf + ((size_t)b * LQ + q0 + c15) * DX + g4 * 8;
#pragma unroll
    for (int ks = 0; ks < 16; ++ks) {
      float4 a0 = *(const float4*)(qrow + ks * 32);
      float4 a1 = *(const float4*)(qrow + ks * 32 + 4);
      half8 f;
      f[0] = (_Float16)(a0.x * LOG2E); f[1] = (_Float16)(a0.y * LOG2E);
      f[2] = (_Float16)(a0.z * LOG2E); f[3] = (_Float16)(a0.w * LOG2E);
      f[4] = (_Float16)(a1.x * LOG2E); f[5] = (_Float16)(a1.y * LOG2E);
      f[6] = (_Float16)(a1.z * LOG2E); f[7] = (_Float16)(a1.w * LOG2E);
      qfrag[ks] = f;
    }
  }

  f32x4 acc[16];
#pragma unroll
  for (int n = 0; n < 16; ++n) acc[n] = (f32x4){0.f, 0.f, 0.f, 0.f};
  float mr = -3.0e38f, lr = 0.f;

  // ---- staging descriptors (4 K-insts + 4 V-insts per wave per chunk)
  const unsigned short* ksrc0[4];
  const unsigned short* vsrc0[4];
  int kdoff[4], vdoff[4];
#pragma unroll
  for (int ii = 0; ii < 4; ++ii) {
    const int i = wave * 4 + ii;        // 0..31
    kdoff[ii] = i * 512;
    ksrc0[ii] = Kh + (size_t)b * LK * DX + (size_t)(lane & 31) * DX
                + (2 * i + (lane >> 5)) * 8;
    const int pv = i >> 3, dblk = (i & 7) * 64;
    vdoff[ii] = pv * 4096 + dblk * 8;
    vsrc0[ii] = Vt + (size_t)b * DVD * LK + (size_t)(dblk + lane) * LK + pv * 8;
  }

  // ---- prologue: stage chunk 0 into buffer 0
#pragma unroll
  for (int ii = 0; ii < 4; ++ii) gload16(ksrc0[ii], &Kl[0][kdoff[ii]]);
#pragma unroll
  for (int ii = 0; ii < 4; ++ii) gload16(vsrc0[ii], &Vl[0][vdoff[ii]]);
  __syncthreads();

  for (int c = 0; c < NCH; ++c) {
    const int cur = c & 1;

    // ---- issue next chunk's staging (in flight across the whole chunk body)
    if (c + 1 < NCH) {
      const size_t kadv = (size_t)(c + 1) * KVB * DX;
      const int    vadv = (c + 1) * KVB;
#pragma unroll
      for (int ii = 0; ii < 4; ++ii) gload16(ksrc0[ii] + kadv, &Kl[cur ^ 1][kdoff[ii]]);
#pragma unroll
      for (int ii = 0; ii < 4; ++ii) gload16(vsrc0[ii] + vadv, &Vl[cur ^ 1][vdoff[ii]]);
    }

    // ---- swapped QK^T: cs = K·Q^T -> lane owns S[kv=rbase+j(+16)][q=c15]
    f32x4 cs0 = {0.f, 0.f, 0.f, 0.f};
    f32x4 cs1 = {0.f, 0.f, 0.f, 0.f};
    {
      const unsigned short* kb = &Kl[cur][c15 * 8 + g4 * 256];
      __builtin_amdgcn_s_setprio(1);
#pragma unroll
      for (int ks = 0; ks < 16; ++ks) {
        const unsigned short* kp = kb + ks * 1024;     // part = ks*4+g4
        half8 a0 = *(const half8*)kp;                  // kv = c15
        half8 a1 = *(const half8*)(kp + 128);          // kv = c15+16
        cs0 = __builtin_amdgcn_mfma_f32_16x16x32_f16(a0, qfrag[ks], cs0, 0, 0, 0);
        cs1 = __builtin_amdgcn_mfma_f32_16x16x32_f16(a1, qfrag[ks], cs1, 0, 0, 0);
      }
      __builtin_amdgcn_s_setprio(0);
    }

    // ---- fully in-wave online softmax (lane's q-row = c15)
    float pm = fmaxf(fmaxf(fmaxf(cs0[0], cs0[1]), fmaxf(cs0[2], cs0[3])),
                     fmaxf(fmaxf(cs1[0], cs1[1]), fmaxf(cs1[2], cs1[3])));
    pm = fmaxf(pm, __shfl_xor(pm, 16, 64));
    pm = fmaxf(pm, __shfl_xor(pm, 32, 64));
    float mnew = fmaxf(mr, pm);
    float scl = exp2f(mr - mnew);
    float p[8];
#pragma unroll
    for (int j = 0; j < 4; ++j) {
      p[j]     = exp2f(cs0[j] - mnew);
      p[4 + j] = exp2f(cs1[j] - mnew);
    }
    float ps = ((p[0] + p[1]) + (p[2] + p[3])) + ((p[4] + p[5]) + (p[6] + p[7]));
    ps += __shfl_xor(ps, 16, 64);
    ps += __shfl_xor(ps, 32, 64);
    lr = lr * scl + ps;
    mr = mnew;

    // ---- wave-private P bounce into PV A-fragment layout (no barrier)
    {
      unsigned short* pb = &Pl[wave][(g4 >> 1) * 128 + c15 * 8 + (g4 & 1) * 4];
      *(unsigned int*)(pb + 0)   = pack2(p[0], p[1]);   // kv = g4*4+0,1
      *(unsigned int*)(pb + 2)   = pack2(p[2], p[3]);   // kv = g4*4+2,3
      *(unsigned int*)(pb + 256) = pack2(p[4], p[5]);   // kv = 16+g4*4+0,1
      *(unsigned int*)(pb + 258) = pack2(p[6], p[7]);   // kv = 16+g4*4+2,3
    }
    if (g4 == 0) sml[wave][c15] = scl;                  // broadcast scl by q-row

    f32x4 sclv = *(const f32x4*)&sml[wave][rbase];      // scl for q=rbase+j
#pragma unroll
    for (int n = 0; n < 16; ++n)
#pragma unroll
      for (int j = 0; j < 4; ++j) acc[n][j] *= sclv[j];

    half8 pa = *(const half8*)&Pl[wave][g4 * 128 + c15 * 8];  // P[q=c15][kv=g4*8+e]

    // ---- PV: acc[n] += P * V[:, d0+n*16+c15]
    {
      const unsigned short* vb = &Vl[cur][g4 * 4096 + (d0 + c15) * 8];
      __builtin_amdgcn_s_setprio(1);
#pragma unroll
      for (int n = 0; n < 16; ++n) {
        half8 bv = *(const half8*)(vb + n * 128);
        acc[n] = __builtin_amdgcn_mfma_f32_16x16x32_f16(pa, bv, acc[n], 0, 0, 0);
      }
      __builtin_amdgcn_s_setprio(0);
    }

    __syncthreads();  // single barrier: drains DMA + guards buffer swap
  }

  // ---- epilogue: relocate l to accumulator rows, O /= l, store f32
  if (g4 == 0) sml[wave][c15] = lr;
  f32x4 lrv = *(const f32x4*)&sml[wave][rbase];
  float inv[4];
#pragma unroll
  for (int j = 0; j < 4; ++j) inv[j] = 1.0f / lrv[j];
  float* ob = Out + ((size_t)b * LQ + q0 + rbase) * DVD + d0 + c15;
#pragma unroll
  for (int n = 0; n < 16; ++n)
#pragma unroll
    for (int j = 0; j < 4; ++j)
      ob[(size_t)j * DVD + n * 16] = acc[n][j] * inv[j];
}

extern "C" void kernel_launch(void* const* d_in, const int* in_sizes, int n_in,
                              void* d_out, int out_size, void* d_ws, size_t ws_size,
                              hipStream_t stream) {
  const float* Qf = (const float*)d_in[0];
  const float* Kf = (const float*)d_in[1];
  const float* Vf = (const float*)d_in[2];
  float* Out = (float*)d_out;

  unsigned short* Kh = (unsigned short*)d_ws;
  unsigned short* Vt = Kh + (size_t)NB * LK * DX;   // 16.7 MB each

  cvt_k<<<4096, 256, 0, stream>>>(Kf, Kh);
  cvt_transpose_v<<<NB * 16 * 8, 256, 0, stream>>>(Vf, Vt);
  attn_fused3<<<NB * (LQ / QBLK), 512, 0, stream>>>(Qf, Kh, Vt, Out);
}

// Round 6
// 109.041 us; speedup vs baseline: 1.3311x; 1.3311x over previous
//
#include <hip/hip_runtime.h>

typedef _Float16 half8 __attribute__((ext_vector_type(8)));
typedef float f32x4 __attribute__((ext_vector_type(4)));
typedef unsigned short u16x8 __attribute__((ext_vector_type(8)));

#define LOG2E 1.44269504088896340736f

constexpr int NB = 16, LQ = 1024, LK = 1024, DX = 512, DVD = 512;
constexpr int QBLK = 64, KVB = 32, NCH = LK / KVB;
constexpr int TILE = KVB * DX;    // 16384 u16 = 32 KB per (b,chunk) tile

static __device__ __forceinline__ unsigned short f2h(float f) {
  union { _Float16 h; unsigned short u; } c; c.h = (_Float16)f; return c.u;
}
static __device__ __forceinline__ unsigned int pack2(float a, float b) {
  union { _Float16 h[2]; unsigned int u; } c;
  c.h[0] = (_Float16)a; c.h[1] = (_Float16)b; return c.u;
}

static __device__ __forceinline__ void gload16(const unsigned short* g, unsigned short* l) {
  __builtin_amdgcn_global_load_lds(
      (const __attribute__((address_space(1))) unsigned int*)g,
      (__attribute__((address_space(3))) unsigned int*)l, 16, 0, 0);
}

// ---- prep: f32 -> f16 with layout bake.
// blocks [0,512):   K -> Kw[b][c][part=x/8 (64)][kv (32)][8]
// blocks [512,1024): V -> Vw[b][c][pv=kv/8 (4)][d (512)][8]
// Both outputs are contiguous 32 KB tiles per (b,c) => attn staging is a
// linear memcpy-style DMA (fully coalesced global reads).
__global__ __launch_bounds__(256) void prep_kv(
    const float* __restrict__ K, const float* __restrict__ V,
    unsigned short* __restrict__ Kw, unsigned short* __restrict__ Vw) {
  __shared__ float tile[32][520];
  const int bidx = blockIdx.x;
  const bool isV = bidx >= NB * NCH;
  const int bc = isV ? bidx - NB * NCH : bidx;      // b*32 + c
  const int t = (int)threadIdx.x;

  // load 32 rows x 512 f32 (one chunk), coalesced
  const float* src = (isV ? V : K) + (size_t)bc * (KVB * DX);
#pragma unroll
  for (int i = 0; i < 16; ++i) {
    int idx = t + i * 256;            // float4 index 0..4095
    int r = idx >> 7;                 // 128 float4 per row
    int cc = (idx & 127) * 4;
    float4 v = *(const float4*)(src + (size_t)idx * 4);
    *(float4*)&tile[r][cc] = v;
  }
  __syncthreads();

  unsigned short* dst = (isV ? Vw : Kw) + (size_t)bc * TILE;
  if (!isV) {
    // output 16B-block obi: p = obi>>5, kv = obi&31; holds K[kv][p*8 .. p*8+7]
#pragma unroll
    for (int k = 0; k < 8; ++k) {
      int obi = t * 8 + k;
      int p = obi >> 5, kv = obi & 31;
      const float* rp = &tile[kv][p * 8];
      u16x8 o = { f2h(rp[0]), f2h(rp[1]), f2h(rp[2]), f2h(rp[3]),
                  f2h(rp[4]), f2h(rp[5]), f2h(rp[6]), f2h(rp[7]) };
      *(u16x8*)(dst + obi * 8) = o;
    }
  } else {
    // output 16B-block vbi: pv = vbi>>9, d = vbi&511; holds V[pv*8+e][d]
#pragma unroll
    for (int k = 0; k < 8; ++k) {
      int vbi = t * 8 + k;
      int pv = vbi >> 9, d = vbi & 511;
      u16x8 o = { f2h(tile[pv * 8 + 0][d]), f2h(tile[pv * 8 + 1][d]),
                  f2h(tile[pv * 8 + 2][d]), f2h(tile[pv * 8 + 3][d]),
                  f2h(tile[pv * 8 + 4][d]), f2h(tile[pv * 8 + 5][d]),
                  f2h(tile[pv * 8 + 6][d]), f2h(tile[pv * 8 + 7][d]) };
      *(u16x8*)(dst + vbi * 8) = o;
    }
  }
}

// ---- main fused attention (round-3 structure, coalesced DMA + defer-max)
__global__ __launch_bounds__(512, 2) void attn_fused4(
    const float* __restrict__ Qf, const unsigned short* __restrict__ Kw,
    const unsigned short* __restrict__ Vw, float* __restrict__ Out) {
  __shared__ __align__(16) unsigned short Kl[2][TILE];
  __shared__ __align__(16) unsigned short Vl[2][TILE];
  __shared__ __align__(16) unsigned short Pl[8][512];
  __shared__ __align__(16) float sml[8][16];

  const int bid = blockIdx.x;
  const int logical = (bid & 7) * 32 + (bid >> 3);  // XCD-chunked: 2 batches/XCD
  const int b  = logical >> 4;
  const int qt = logical & 15;
  const int tid = (int)threadIdx.x;
  const int lane = tid & 63;
  const int wave = tid >> 6;            // 0..7
  const int wq = wave >> 1, wd = wave & 1;
  const int q0 = qt * QBLK + wq * 16;
  const int d0 = wd * 256;
  const int c15 = lane & 15;
  const int g4  = lane >> 4;
  const int rbase = g4 * 4;

  // ---- Q fragments (pre-scaled by LOG2E; softmax in log2 units)
  half8 qfrag[16];
  {
    const float* qrow = Qf + ((size_t)b * LQ + q0 + c15) * DX + g4 * 8;
#pragma unroll
    for (int ks = 0; ks < 16; ++ks) {
      float4 a0 = *(const float4*)(qrow + ks * 32);
      float4 a1 = *(const float4*)(qrow + ks * 32 + 4);
      half8 f;
      f[0] = (_Float16)(a0.x * LOG2E); f[1] = (_Float16)(a0.y * LOG2E);
      f[2] = (_Float16)(a0.z * LOG2E); f[3] = (_Float16)(a0.w * LOG2E);
      f[4] = (_Float16)(a1.x * LOG2E); f[5] = (_Float16)(a1.y * LOG2E);
      f[6] = (_Float16)(a1.z * LOG2E); f[7] = (_Float16)(a1.w * LOG2E);
      qfrag[ks] = f;
    }
  }

  f32x4 acc[16];
#pragma unroll
  for (int n = 0; n < 16; ++n) acc[n] = (f32x4){0.f, 0.f, 0.f, 0.f};
  float mr = -3.0e38f, lr = 0.f;

  // ---- coalesced staging: per wave a 4 KB slice of each 32 KB tile
  const unsigned short* kg = Kw + (size_t)b * NCH * TILE + wave * 2048 + lane * 8;
  const unsigned short* vg = Vw + (size_t)b * NCH * TILE + wave * 2048 + lane * 8;
  const int ldso = wave * 2048;

  // prologue: stage chunk 0 into buffer 0
#pragma unroll
  for (int ii = 0; ii < 4; ++ii) gload16(kg + ii * 512, &Kl[0][ldso + ii * 512]);
#pragma unroll
  for (int ii = 0; ii < 4; ++ii) gload16(vg + ii * 512, &Vl[0][ldso + ii * 512]);
  __syncthreads();

  for (int c = 0; c < NCH; ++c) {
    const int cur = c & 1;

    // ---- prefetch next chunk (in flight across the whole chunk body)
    if (c + 1 < NCH) {
      const size_t adv = (size_t)(c + 1) * TILE;
#pragma unroll
      for (int ii = 0; ii < 4; ++ii) gload16(kg + adv + ii * 512, &Kl[cur ^ 1][ldso + ii * 512]);
#pragma unroll
      for (int ii = 0; ii < 4; ++ii) gload16(vg + adv + ii * 512, &Vl[cur ^ 1][ldso + ii * 512]);
    }

    // ---- swapped QK^T: lane owns S[kv=rbase+j(+16)][q=c15]
    f32x4 cs0 = {0.f, 0.f, 0.f, 0.f};
    f32x4 cs1 = {0.f, 0.f, 0.f, 0.f};
    {
      const unsigned short* kb = &Kl[cur][c15 * 8 + g4 * 256];
      __builtin_amdgcn_s_setprio(1);
#pragma unroll
      for (int ks = 0; ks < 16; ++ks) {
        const unsigned short* kp = kb + ks * 1024;   // part = ks*4+g4
        half8 a0 = *(const half8*)kp;                // kv = c15
        half8 a1 = *(const half8*)(kp + 128);        // kv = c15+16
        cs0 = __builtin_amdgcn_mfma_f32_16x16x32_f16(a0, qfrag[ks], cs0, 0, 0, 0);
        cs1 = __builtin_amdgcn_mfma_f32_16x16x32_f16(a1, qfrag[ks], cs1, 0, 0, 0);
      }
      __builtin_amdgcn_s_setprio(0);
    }

    // ---- in-wave online softmax with defer-max (T13, THR=8 in log2 units)
    float pm = fmaxf(fmaxf(fmaxf(cs0[0], cs0[1]), fmaxf(cs0[2], cs0[3])),
                     fmaxf(fmaxf(cs1[0], cs1[1]), fmaxf(cs1[2], cs1[3])));
    pm = fmaxf(pm, __shfl_xor(pm, 16, 64));
    pm = fmaxf(pm, __shfl_xor(pm, 32, 64));
    const bool resc = __any(pm > mr + 8.0f);
    float scl = 1.0f;
    if (resc) {
      float mnew = fmaxf(mr, pm);
      scl = exp2f(mr - mnew);
      mr = mnew;
    }
    float p[8];
#pragma unroll
    for (int j = 0; j < 4; ++j) {
      p[j]     = exp2f(cs0[j] - mr);
      p[4 + j] = exp2f(cs1[j] - mr);
    }
    float ps = ((p[0] + p[1]) + (p[2] + p[3])) + ((p[4] + p[5]) + (p[6] + p[7]));
    ps += __shfl_xor(ps, 16, 64);
    ps += __shfl_xor(ps, 32, 64);

    if (resc) {
      if (g4 == 0) sml[wave][c15] = scl;            // relocate scl to acc rows
      lr = lr * scl + ps;
    } else {
      lr += ps;
    }

    // ---- wave-private P bounce into PV A-fragment layout (no barrier)
    {
      unsigned short* pb = &Pl[wave][(g4 >> 1) * 128 + c15 * 8 + (g4 & 1) * 4];
      *(unsigned int*)(pb + 0)   = pack2(p[0], p[1]);
      *(unsigned int*)(pb + 2)   = pack2(p[2], p[3]);
      *(unsigned int*)(pb + 256) = pack2(p[4], p[5]);
      *(unsigned int*)(pb + 258) = pack2(p[6], p[7]);
    }

    if (resc) {
      f32x4 sclv = *(const f32x4*)&sml[wave][rbase];
#pragma unroll
      for (int n = 0; n < 16; ++n)
#pragma unroll
        for (int j = 0; j < 4; ++j) acc[n][j] *= sclv[j];
    }

    half8 pa = *(const half8*)&Pl[wave][g4 * 128 + c15 * 8];  // P[q=c15][kv=g4*8+e]

    // ---- PV: acc[n] += P * V[:, d0+n*16+c15]
    {
      const unsigned short* vb = &Vl[cur][g4 * 4096 + (d0 + c15) * 8];
      __builtin_amdgcn_s_setprio(1);
#pragma unroll
      for (int n = 0; n < 16; ++n) {
        half8 bv = *(const half8*)(vb + n * 128);
        acc[n] = __builtin_amdgcn_mfma_f32_16x16x32_f16(pa, bv, acc[n], 0, 0, 0);
      }
      __builtin_amdgcn_s_setprio(0);
    }

    __syncthreads();  // single barrier: drains DMA + guards buffer swap
  }

  // ---- epilogue: relocate l to accumulator rows, O /= l, store f32
  if (g4 == 0) sml[wave][c15] = lr;
  f32x4 lrv = *(const f32x4*)&sml[wave][rbase];
  float inv[4];
#pragma unroll
  for (int j = 0; j < 4; ++j) inv[j] = 1.0f / lrv[j];
  float* ob = Out + ((size_t)b * LQ + q0 + rbase) * DVD + d0 + c15;
#pragma unroll
  for (int n = 0; n < 16; ++n)
#pragma unroll
    for (int j = 0; j < 4; ++j)
      ob[(size_t)j * DVD + n * 16] = acc[n][j] * inv[j];
}

extern "C" void kernel_launch(void* const* d_in, const int* in_sizes, int n_in,
                              void* d_out, int out_size, void* d_ws, size_t ws_size,
                              hipStream_t stream) {
  const float* Qf = (const float*)d_in[0];
  const float* Kf = (const float*)d_in[1];
  const float* Vf = (const float*)d_in[2];
  float* Out = (float*)d_out;

  unsigned short* Kw = (unsigned short*)d_ws;
  unsigned short* Vw = Kw + (size_t)NB * NCH * TILE;   // 16.7 MB each

  prep_kv<<<NB * NCH * 2, 256, 0, stream>>>(Kf, Vf, Kw, Vw);
  attn_fused4<<<NB * (LQ / QBLK), 512, 0, stream>>>(Qf, Kw, Vw, Out);
}

// Round 7
// 95.630 us; speedup vs baseline: 1.5178x; 1.1402x over previous
//
#include <hip/hip_runtime.h>

typedef _Float16 half8 __attribute__((ext_vector_type(8)));
typedef float f32x4 __attribute__((ext_vector_type(4)));
typedef unsigned short u16x8 __attribute__((ext_vector_type(8)));

#define LOG2E 1.44269504088896340736f

constexpr int NB = 16, LQ = 1024, LK = 1024, DX = 512, DVD = 512;
constexpr int QBLK = 64, KVB = 64, NCH = LK / KVB;   // 16 chunks of 64 kv
constexpr int TILE = KVB * DX;                        // 32768 u16 = 64 KB

static __device__ __forceinline__ unsigned short f2h(float f) {
  union { _Float16 h; unsigned short u; } c; c.h = (_Float16)f; return c.u;
}
static __device__ __forceinline__ unsigned int pack2(float a, float b) {
  union { _Float16 h[2]; unsigned int u; } c;
  c.h[0] = (_Float16)a; c.h[1] = (_Float16)b; return c.u;
}
static __device__ __forceinline__ void gload16(const unsigned short* g, unsigned short* l) {
  __builtin_amdgcn_global_load_lds(
      (const __attribute__((address_space(1))) unsigned int*)g,
      (__attribute__((address_space(3))) unsigned int*)l, 16, 0, 0);
}

// ---- prep: f32 -> f16 with layout bake into 64-KB (b,c) tiles.
// K -> Kw[b][c][part=x/8 (64)][kv (64)][8]
// V -> Vw[b][c][pv=kv/8 (8)][d (512)][8]
// Each block handles a 32-kv half of one chunk. 1024 blocks total.
__global__ __launch_bounds__(256) void prep_kv(
    const float* __restrict__ K, const float* __restrict__ V,
    unsigned short* __restrict__ Kw, unsigned short* __restrict__ Vw) {
  __shared__ float tile[32][520];
  const int bidx = blockIdx.x;
  const bool isV = bidx >= NB * NCH * 2;
  const int r = isV ? bidx - NB * NCH * 2 : bidx;   // b*32 + c*2 + half
  const int b = r >> 5, sub = r & 31, c = sub >> 1, half = sub & 1;
  const int t = (int)threadIdx.x;

  const float* src = (isV ? V : K) + ((size_t)b * LK + c * 64 + half * 32) * DX;
#pragma unroll
  for (int i = 0; i < 16; ++i) {
    int idx = t + i * 256;            // float4 index 0..4095
    int rr = idx >> 7, cc = (idx & 127) * 4;
    float4 v = *(const float4*)(src + (size_t)idx * 4);
    *(float4*)&tile[rr][cc] = v;
  }
  __syncthreads();

  unsigned short* dst = (isV ? Vw : Kw) + (size_t)(b * NCH + c) * TILE;
  if (!isV) {
    // 16B block obi: p = obi>>5 (0..63), kvloc = obi&31
#pragma unroll
    for (int k = 0; k < 8; ++k) {
      int obi = t * 8 + k;
      int p = obi >> 5, kvloc = obi & 31;
      const float* rp = &tile[kvloc][p * 8];
      u16x8 o = { f2h(rp[0]), f2h(rp[1]), f2h(rp[2]), f2h(rp[3]),
                  f2h(rp[4]), f2h(rp[5]), f2h(rp[6]), f2h(rp[7]) };
      *(u16x8*)(dst + p * 512 + (half * 32 + kvloc) * 8) = o;
    }
  } else {
    // 16B block vbi: pvloc = vbi>>9 (0..3), d = vbi&511
#pragma unroll
    for (int k = 0; k < 8; ++k) {
      int vbi = t * 8 + k;
      int pvloc = vbi >> 9, d = vbi & 511;
      u16x8 o = { f2h(tile[pvloc * 8 + 0][d]), f2h(tile[pvloc * 8 + 1][d]),
                  f2h(tile[pvloc * 8 + 2][d]), f2h(tile[pvloc * 8 + 3][d]),
                  f2h(tile[pvloc * 8 + 4][d]), f2h(tile[pvloc * 8 + 5][d]),
                  f2h(tile[pvloc * 8 + 6][d]), f2h(tile[pvloc * 8 + 7][d]) };
      *(u16x8*)(dst + (half * 4 + pvloc) * 4096 + d * 8) = o;
    }
  }
}

// ---- main fused attention: 2 wq (32 q) x 4 wd; kv-quarter QK, d-quarter PV
__global__ __launch_bounds__(512, 2) void attn_fused5(
    const float* __restrict__ Qf, const unsigned short* __restrict__ Kw,
    const unsigned short* __restrict__ Vw, float* __restrict__ Out) {
  __shared__ __align__(16) unsigned short Kl[TILE];    // 64 KB single buffer
  __shared__ __align__(16) unsigned short Vl[TILE];    // 64 KB single buffer
  __shared__ __align__(16) unsigned short Pl[4096];    // [wq][pp 8][q 32][8]
  __shared__ __align__(16) float pmax[2][4][32];
  __shared__ __align__(16) float psum[2][4][32];
  __shared__ __align__(16) float sml[2][32];

  const int bid = blockIdx.x;
  const int logical = (bid & 7) * 32 + (bid >> 3);  // XCD-chunked
  const int b  = logical >> 4;
  const int qt = logical & 15;
  const int tid = (int)threadIdx.x;
  const int lane = tid & 63;
  const int wave = tid >> 6;            // 0..7
  const int wq = wave >> 2;             // 0..1 : 32 q rows
  const int wd = wave & 3;              // 0..3 : QK kv-quarter / PV d-quarter
  const int q0 = qt * QBLK + wq * 32;
  const int d0 = wd * 128;
  const int c15 = lane & 15;
  const int g4  = lane >> 4;
  const int rbase = g4 * 4;

  // ---- Q fragments: 32 rows (2 qsubs x 16 ks), pre-scaled by LOG2E
  half8 qfrag[2][16];
#pragma unroll
  for (int s = 0; s < 2; ++s) {
    const float* qrow = Qf + ((size_t)b * LQ + q0 + s * 16 + c15) * DX + g4 * 8;
#pragma unroll
    for (int ks = 0; ks < 16; ++ks) {
      float4 a0 = *(const float4*)(qrow + ks * 32);
      float4 a1 = *(const float4*)(qrow + ks * 32 + 4);
      half8 f;
      f[0] = (_Float16)(a0.x * LOG2E); f[1] = (_Float16)(a0.y * LOG2E);
      f[2] = (_Float16)(a0.z * LOG2E); f[3] = (_Float16)(a0.w * LOG2E);
      f[4] = (_Float16)(a1.x * LOG2E); f[5] = (_Float16)(a1.y * LOG2E);
      f[6] = (_Float16)(a1.z * LOG2E); f[7] = (_Float16)(a1.w * LOG2E);
      qfrag[s][ks] = f;
    }
  }

  f32x4 acc[2][8];
#pragma unroll
  for (int s = 0; s < 2; ++s)
#pragma unroll
    for (int n = 0; n < 8; ++n) acc[s][n] = (f32x4){0.f, 0.f, 0.f, 0.f};
  float mr[2] = { -3.0e38f, -3.0e38f };
  float lr[2] = { 0.f, 0.f };

  // ---- staging bases: per wave an 8-KB linear slice of each 64-KB tile
  const unsigned short* kg = Kw + (size_t)b * NCH * TILE + wave * 4096 + lane * 8;
  const unsigned short* vg = Vw + (size_t)b * NCH * TILE + wave * 4096 + lane * 8;
  unsigned short* kl = &Kl[wave * 4096];
  unsigned short* vl = &Vl[wave * 4096];

  // prologue: stage chunk 0 (K and V), full drain
#pragma unroll
  for (int ii = 0; ii < 8; ++ii) gload16(kg + ii * 512, kl + ii * 512);
#pragma unroll
  for (int ii = 0; ii < 8; ++ii) gload16(vg + ii * 512, vl + ii * 512);
  __syncthreads();

  for (int c = 0; c < NCH; ++c) {
    // ---- QK^T: wave owns kv quarter wd (16 kv) x 32 q (2 qsubs)
    f32x4 cs0 = {0.f, 0.f, 0.f, 0.f};
    f32x4 cs1 = {0.f, 0.f, 0.f, 0.f};
    {
      const unsigned short* kb = &Kl[(wd * 16 + c15) * 8 + g4 * 512];
      __builtin_amdgcn_s_setprio(1);
#pragma unroll
      for (int ks = 0; ks < 16; ++ks) {
        half8 af = *(const half8*)(kb + ks * 2048);   // part = ks*4+g4
        cs0 = __builtin_amdgcn_mfma_f32_16x16x32_f16(af, qfrag[0][ks], cs0, 0, 0, 0);
        cs1 = __builtin_amdgcn_mfma_f32_16x16x32_f16(af, qfrag[1][ks], cs1, 0, 0, 0);
      }
      __builtin_amdgcn_s_setprio(0);
    }

    // ---- partial row-max over own 16 kv
    float pm0 = fmaxf(fmaxf(cs0[0], cs0[1]), fmaxf(cs0[2], cs0[3]));
    float pm1 = fmaxf(fmaxf(cs1[0], cs1[1]), fmaxf(cs1[2], cs1[3]));
    pm0 = fmaxf(pm0, __shfl_xor(pm0, 16, 64)); pm0 = fmaxf(pm0, __shfl_xor(pm0, 32, 64));
    pm1 = fmaxf(pm1, __shfl_xor(pm1, 16, 64)); pm1 = fmaxf(pm1, __shfl_xor(pm1, 32, 64));
    if (g4 == 0) { pmax[wq][wd][c15] = pm0; pmax[wq][wd][16 + c15] = pm1; }

    // B1: pmax visible; all QK reads of Kl done -> safe to overwrite Kl
    asm volatile("s_waitcnt lgkmcnt(0)" ::: "memory");
    __builtin_amdgcn_s_barrier();
    __builtin_amdgcn_sched_barrier(0);

    // ---- issue K(c+1) DMA into Kl (covers softmax2 + PV)
    if (c + 1 < NCH) {
      const unsigned short* ks_ = kg + (size_t)(c + 1) * TILE;
#pragma unroll
      for (int ii = 0; ii < 8; ++ii) gload16(ks_ + ii * 512, kl + ii * 512);
    }

    // ---- combine maxes, defer-max, p, partial sums
    float pa0 = fmaxf(fmaxf(pmax[wq][0][c15], pmax[wq][1][c15]),
                      fmaxf(pmax[wq][2][c15], pmax[wq][3][c15]));
    float pa1 = fmaxf(fmaxf(pmax[wq][0][16 + c15], pmax[wq][1][16 + c15]),
                      fmaxf(pmax[wq][2][16 + c15], pmax[wq][3][16 + c15]));
    const bool resc = __any((pa0 > mr[0] + 8.0f) || (pa1 > mr[1] + 8.0f));
    float scl0 = 1.0f, scl1 = 1.0f;
    if (resc) {
      float mn0 = fmaxf(mr[0], pa0), mn1 = fmaxf(mr[1], pa1);
      scl0 = exp2f(mr[0] - mn0); scl1 = exp2f(mr[1] - mn1);
      mr[0] = mn0; mr[1] = mn1;
      if (wd == 0 && g4 == 0) { sml[wq][c15] = scl0; sml[wq][16 + c15] = scl1; }
    }
    float p0[4], p1[4];
#pragma unroll
    for (int j = 0; j < 4; ++j) {
      p0[j] = exp2f(cs0[j] - mr[0]);
      p1[j] = exp2f(cs1[j] - mr[1]);
    }
    float ps0 = (p0[0] + p0[1]) + (p0[2] + p0[3]);
    float ps1 = (p1[0] + p1[1]) + (p1[2] + p1[3]);
    ps0 += __shfl_xor(ps0, 16, 64); ps0 += __shfl_xor(ps0, 32, 64);
    ps1 += __shfl_xor(ps1, 16, 64); ps1 += __shfl_xor(ps1, 32, 64);
    if (g4 == 0) { psum[wq][wd][c15] = ps0; psum[wq][wd][16 + c15] = ps1; }

    // ---- P write: kv = wd*16 + rbase + j, q = s*16 + c15 (b64 per qsub)
    {
      unsigned short* pb = &Pl[wq * 2048 + (wd * 2 + (g4 >> 1)) * 256
                               + c15 * 8 + (g4 & 1) * 4];
      uint2 w0 = { pack2(p0[0], p0[1]), pack2(p0[2], p0[3]) };
      uint2 w1 = { pack2(p1[0], p1[1]), pack2(p1[2], p1[3]) };
      *(uint2*)pb = w0;
      *(uint2*)(pb + 128) = w1;
    }

    // B2: P/psum/sml visible; counted vmcnt -> V(c) landed, K(c+1) in flight
    if (c + 1 < NCH) asm volatile("s_waitcnt vmcnt(8) lgkmcnt(0)" ::: "memory");
    else             asm volatile("s_waitcnt vmcnt(0) lgkmcnt(0)" ::: "memory");
    __builtin_amdgcn_s_barrier();
    __builtin_amdgcn_sched_barrier(0);

    // ---- l update
    lr[0] = lr[0] * scl0 + (psum[wq][0][c15] + psum[wq][1][c15])
                         + (psum[wq][2][c15] + psum[wq][3][c15]);
    lr[1] = lr[1] * scl1 + (psum[wq][0][16 + c15] + psum[wq][1][16 + c15])
                         + (psum[wq][2][16 + c15] + psum[wq][3][16 + c15]);

    if (resc) {
      f32x4 sv0 = *(const f32x4*)&sml[wq][rbase];
      f32x4 sv1 = *(const f32x4*)&sml[wq][16 + rbase];
#pragma unroll
      for (int n = 0; n < 8; ++n)
#pragma unroll
        for (int j = 0; j < 4; ++j) {
          acc[0][n][j] *= sv0[j];
          acc[1][n][j] *= sv1[j];
        }
    }

    // ---- PV: d quarter wd (128 cols), kv halves h=0,1
    __builtin_amdgcn_s_setprio(1);
#pragma unroll
    for (int h = 0; h < 2; ++h) {
      half8 paf0 = *(const half8*)&Pl[wq * 2048 + (h * 4 + g4) * 256 + c15 * 8];
      half8 paf1 = *(const half8*)&Pl[wq * 2048 + (h * 4 + g4) * 256 + (16 + c15) * 8];
      const unsigned short* vb = &Vl[(h * 4 + g4) * 4096 + (d0 + c15) * 8];
#pragma unroll
      for (int n = 0; n < 8; ++n) {
        half8 bv = *(const half8*)(vb + n * 128);
        acc[0][n] = __builtin_amdgcn_mfma_f32_16x16x32_f16(paf0, bv, acc[0][n], 0, 0, 0);
        acc[1][n] = __builtin_amdgcn_mfma_f32_16x16x32_f16(paf1, bv, acc[1][n], 0, 0, 0);
      }
    }
    __builtin_amdgcn_s_setprio(0);

    // B3: all PV reads of Vl done + K(c+1) drained -> safe to overwrite Vl
    asm volatile("s_waitcnt vmcnt(0) lgkmcnt(0)" ::: "memory");
    __builtin_amdgcn_s_barrier();
    __builtin_amdgcn_sched_barrier(0);

    // ---- issue V(c+1) DMA into Vl (covers next QK + softmax)
    if (c + 1 < NCH) {
      const unsigned short* vs_ = vg + (size_t)(c + 1) * TILE;
#pragma unroll
      for (int ii = 0; ii < 8; ++ii) gload16(vs_ + ii * 512, vl + ii * 512);
    }
  }

  // ---- epilogue: relocate l to accumulator rows, O /= l, store f32
  if (wd == 0 && g4 == 0) { sml[wq][c15] = lr[0]; sml[wq][16 + c15] = lr[1]; }
  asm volatile("s_waitcnt lgkmcnt(0)" ::: "memory");
  __builtin_amdgcn_s_barrier();
  __builtin_amdgcn_sched_barrier(0);

#pragma unroll
  for (int s = 0; s < 2; ++s) {
    f32x4 lrv = *(const f32x4*)&sml[wq][s * 16 + rbase];
    float inv[4];
#pragma unroll
    for (int j = 0; j < 4; ++j) inv[j] = 1.0f / lrv[j];
    float* ob = Out + ((size_t)b * LQ + q0 + s * 16 + rbase) * DVD + d0 + c15;
#pragma unroll
    for (int n = 0; n < 8; ++n)
#pragma unroll
      for (int j = 0; j < 4; ++j)
        ob[(size_t)j * DVD + n * 16] = acc[s][n][j] * inv[j];
  }
}

extern "C" void kernel_launch(void* const* d_in, const int* in_sizes, int n_in,
                              void* d_out, int out_size, void* d_ws, size_t ws_size,
                              hipStream_t stream) {
  const float* Qf = (const float*)d_in[0];
  const float* Kf = (const float*)d_in[1];
  const float* Vf = (const float*)d_in[2];
  float* Out = (float*)d_out;

  unsigned short* Kw = (unsigned short*)d_ws;
  unsigned short* Vw = Kw + (size_t)NB * NCH * TILE;   // 16.7 MB each

  prep_kv<<<NB * NCH * 2 * 2, 256, 0, stream>>>(Kf, Vf, Kw, Vw);
  attn_fused5<<<NB * (LQ / QBLK), 512, 0, stream>>>(Qf, Kw, Vw, Out);
}